// Round 12
// baseline (160.208 us; speedup 1.0000x reference)
//
#include <hip/hip_runtime.h>
#include <hip/hip_cooperative_groups.h>

// SwapV2: Gaussian-weighted separable soft gather — MFMA, wave-owns-channels.
//   t'[u][p] = sum_v X[u][v] * wx[v][p]     (bf16 MFMA, A = X RNE bf16 plane,
//                                            B = wx RNE bf16)
//   out[p]   = sum_u wy[u][p] * t'[u][p] * invZ[p]   (fp32 VALU stage-2)
// R12 = R11 (best, 80.7us) with the preconvert kernel FUSED via cooperative
// launch: each of 512 blocks converts 1/512 of X -> grid.sync() -> R11 body.
// Removes one dispatch + graph-node gap (~6us addressable). Co-residency:
// 512 blocks at 2 blocks/CU (190 VGPR, 28.4KB LDS) exactly fits; if the
// cooperative launch errors (capture/occupancy), fall back to the proven
// R11 two-kernel path in the same call.

#define BB 8
#define CC 32
#define HH 64
#define WW 64

typedef __attribute__((ext_vector_type(8))) short short8;   // 8 bf16 (4 VGPRs)
typedef __attribute__((ext_vector_type(4))) float f32x4;    // 4 fp32
typedef unsigned int uint;

__device__ __forceinline__ uint rn_bf16(float f) {
    uint u = __float_as_uint(f);
    return (u + 0x7FFFu + ((u >> 16) & 1u)) >> 16;   // round-to-nearest-even
}

// ---------------- standalone pass 1 (fallback path) ----------------
__global__ void preconvert_kernel(const float* __restrict__ x, uint* __restrict__ hi)
{
    const int n = BB * CC * HH * WW / 2;     // packed bf16-pair count
    int idx = blockIdx.x * blockDim.x + threadIdx.x;
    for (; idx < n; idx += gridDim.x * blockDim.x) {
        const float2 d = ((const float2*)x)[idx];
        hi[idx] = rn_bf16(d.x) | (rn_bf16(d.y) << 16);
    }
}

// ---------------- main-kernel LDS layout (bytes) ----------------
// WYS[u][66] fp32 : 64*66*4 = 16896  (stride 66: hoist reads <=2-way banked)
// WXH[p][36] uint : 64*144  =  9216
// SUM 512 fp32    :            2048
// INVZ 64 fp32    :             256
#define WYS_OFF   0
#define WXH_OFF   16896
#define SUM_OFF   26112
#define INVZ_OFF  28160
#define LDS_BYTES 28416

// R11 body, shared by the cooperative and two-kernel variants.
__device__ __forceinline__
void swap_body(const uint* __restrict__ xhi,
               const float* __restrict__ exPx, const float* __restrict__ exPy,
               const float* __restrict__ sigmax, const float* __restrict__ sigmay,
               float* __restrict__ out, char* lds)
{
    const int t    = threadIdx.x;
    const int lane = t & 63;
    const int w    = t >> 6;          // wave id -> channel octet
    const int q    = (t >> 4) & 3;    // quad within wave
    const int ln   = t & 15;
    const int bid  = blockIdx.x;      // (i << 3) | b  (XCD heuristic: batch in low bits)
    const int b    = bid & 7;
    const int i    = bid >> 3;
    const int bi   = b * 64 + i;

    // -------- prologue: channels 0 AND 1 issued before the exp phase --------
    const int cplane0 = b * CC + w * 8;                 // absolute (b,c) plane
    const uint* xbase = xhi + (size_t)cplane0 * 2048 + ln * 32 + q * 4;
    union AU { uint4 v; short8 s; };
    AU abuf[2][4][2];
    #pragma unroll
    for (int cc = 0; cc < 2; ++cc)
        #pragma unroll
        for (int mt = 0; mt < 4; ++mt) {
            abuf[cc][mt][0].v = *(const uint4*)(xbase + cc * 2048 + mt * 512);        // ks=0
            abuf[cc][mt][1].v = *(const uint4*)(xbase + cc * 2048 + mt * 512 + 16);   // ks=1
        }

    float* WYS = (float*)(lds + WYS_OFF);

    // -------- phase 0: per-pixel weights (wy fp32; wx RNE bf16, B-layout) --------
    {
        const int p = lane;           // pixel j of this row
        const int g = w;              // coord group (16 coords)
        const int pixBase = bi * 64 + p;
        const float ey = exPy[pixBase], ex = exPx[pixBase];
        const float isy = 1.0f / sigmay[pixBase], isx = 1.0f / sigmax[pixBase];
        float sy = 0.0f, sx = 0.0f;
        #pragma unroll
        for (int k = 0; k < 16; ++k) {
            const int u = g * 16 + k;
            const float dy = ((float)u - ey) * isy;
            const float wy = __expf(-0.5f * dy * dy);
            WYS[u * 66 + p] = wy;
            sy += wy;
        }
        uint* WXH = (uint*)(lds + WXH_OFF);
        #pragma unroll
        for (int j = 0; j < 8; ++j) {
            const int v0 = g * 16 + 2 * j;
            const float dx0 = ((float)v0       - ex) * isx;
            const float dx1 = ((float)(v0 + 1) - ex) * isx;
            const float wx0 = __expf(-0.5f * dx0 * dx0);
            const float wx1 = __expf(-0.5f * dx1 * dx1);
            sx += wx0 + wx1;
            WXH[p * 36 + g * 8 + j] = rn_bf16(wx0) | (rn_bf16(wx1) << 16);
        }
        float* SUMY = (float*)(lds + SUM_OFF);
        float* SUMX = SUMY + 256;
        SUMY[g * 64 + p] = sy;
        SUMX[g * 64 + p] = sx;
    }
    __syncthreads();
    float* INVZ = (float*)(lds + INVZ_OFF);
    if (t < 64) {
        float* SUMY = (float*)(lds + SUM_OFF);
        float* SUMX = SUMY + 256;
        const float sy = SUMY[t] + SUMY[64 + t] + SUMY[128 + t] + SUMY[192 + t];
        const float sx = SUMX[t] + SUMX[64 + t] + SUMX[128 + t] + SUMX[192 + t];
        INVZ[t] = 1.0f / (sy * sx + 1e-8f);
    }
    __syncthreads();

    // -------- hoist ALL channel-invariants into registers (one-time) --------
    short8 bh[4][2];
    #pragma unroll
    for (int nt = 0; nt < 4; ++nt)
        #pragma unroll
        for (int ks = 0; ks < 2; ++ks)
            bh[nt][ks] = *(const short8*)(lds + WXH_OFF + (nt * 16 + ln) * 144 + ks * 64 + q * 16);
    float wyz[4][4][4];
    #pragma unroll
    for (int nt = 0; nt < 4; ++nt) {
        const float iz = INVZ[nt * 16 + ln];
        #pragma unroll
        for (int mt = 0; mt < 4; ++mt)
            #pragma unroll
            for (int rr = 0; rr < 4; ++rr)
                wyz[mt][nt][rr] = WYS[(mt * 16 + q * 4 + rr) * 66 + nt * 16 + ln] * iz;
    }
    // ------- from here on: NO barriers; waves fully independent -------

    float* obase = out + (size_t)cplane0 * 4096 + i * 64 + lane;

    #pragma unroll
    for (int c = 0; c < 8; ++c) {
        float ps[4] = {0.f, 0.f, 0.f, 0.f};
        #pragma unroll
        for (int mt = 0; mt < 4; ++mt) {
            f32x4 acc[4];
            #pragma unroll
            for (int nt = 0; nt < 4; ++nt) acc[nt] = (f32x4){0.f, 0.f, 0.f, 0.f};
            #pragma unroll
            for (int nt = 0; nt < 4; ++nt) {
                acc[nt] = __builtin_amdgcn_mfma_f32_16x16x32_bf16(abuf[c & 1][mt][0].s, bh[nt][0], acc[nt], 0, 0, 0);
                acc[nt] = __builtin_amdgcn_mfma_f32_16x16x32_bf16(abuf[c & 1][mt][1].s, bh[nt][1], acc[nt], 0, 0, 0);
            }
            #pragma unroll
            for (int nt = 0; nt < 4; ++nt)
                ps[nt] += acc[nt][0] * wyz[mt][nt][0] + acc[nt][1] * wyz[mt][nt][1]
                        + acc[nt][2] * wyz[mt][nt][2] + acc[nt][3] * wyz[mt][nt][3];
        }
        // distance-2 prefetch: channel c+2 into slot c&1 (just consumed above)
        if (c + 2 < 8) {
            const uint* xn = xbase + (c + 2) * 2048;
            #pragma unroll
            for (int mt = 0; mt < 4; ++mt) {
                abuf[c & 1][mt][0].v = *(const uint4*)(xn + mt * 512);
                abuf[c & 1][mt][1].v = *(const uint4*)(xn + mt * 512 + 16);
            }
        }
        #pragma unroll
        for (int nt = 0; nt < 4; ++nt) {
            ps[nt] += __shfl_xor(ps[nt], 16, 64);
            ps[nt] += __shfl_xor(ps[nt], 32, 64);
        }
        const float po = (q == 0) ? ps[0] : (q == 1) ? ps[1] : (q == 2) ? ps[2] : ps[3];
        obase[(size_t)c * 4096] = po;
    }
}

// ---------------- R12: cooperative fused kernel ----------------
__global__ __launch_bounds__(256, 2)
void swap_coop_kernel(const float* __restrict__ inp, uint* __restrict__ xhi,
                      const float* __restrict__ exPx, const float* __restrict__ exPy,
                      const float* __restrict__ sigmax, const float* __restrict__ sigmay,
                      float* __restrict__ out)
{
    __shared__ __align__(16) char lds[LDS_BYTES];
    // phase A: whole grid converts X -> bf16 plane (4 pairs/thread, coalesced)
    {
        const int gtid = blockIdx.x * 256 + threadIdx.x;   // 131072 threads
        const float2* src = (const float2*)inp;
        #pragma unroll
        for (int k = 0; k < 4; ++k) {
            const int idx = gtid + k * 131072;             // covers 524288 pairs
            const float2 d = src[idx];
            xhi[idx] = rn_bf16(d.x) | (rn_bf16(d.y) << 16);
        }
    }
    cooperative_groups::this_grid().sync();
    // phase B: R11 body
    swap_body(xhi, exPx, exPy, sigmax, sigmay, out, lds);
}

// ---------------- R11 two-kernel main (fallback if coop launch fails) ----------------
__global__ __launch_bounds__(256, 2)
void swap_mfma_kernel(const uint* __restrict__ xhi,
                      const float* __restrict__ exPx, const float* __restrict__ exPy,
                      const float* __restrict__ sigmax, const float* __restrict__ sigmay,
                      float* __restrict__ out)
{
    __shared__ __align__(16) char lds[LDS_BYTES];
    swap_body(xhi, exPx, exPy, sigmax, sigmay, out, lds);
}

// ---------------- fallback (R4 proven fused kernel, fp32 loads + A split) ----------------
__device__ __forceinline__ void split_pair(float f0, float f1, uint& hi, uint& lo) {
    const uint u0 = __float_as_uint(f0), u1 = __float_as_uint(f1);
    hi = (u0 >> 16) | (u1 & 0xFFFF0000u);
    const float l0 = f0 - __uint_as_float(u0 & 0xFFFF0000u);
    const float l1 = f1 - __uint_as_float(u1 & 0xFFFF0000u);
    lo = (__float_as_uint(l0) >> 16) | (__float_as_uint(l1) & 0xFFFF0000u);
}

#define FB_WYS_OFF   0
#define FB_WXH_OFF   16640
#define FB_SUM_OFF   25856
#define FB_INVZ_OFF  27904
#define FB_LDS_BYTES 28160
#define FB_RED_OFF   0

__global__ __launch_bounds__(256, 4)
void swap_fused_kernel(const float* __restrict__ inp,
                       const float* __restrict__ exPx, const float* __restrict__ exPy,
                       const float* __restrict__ sigmax, const float* __restrict__ sigmay,
                       float* __restrict__ out)
{
    __shared__ __align__(16) char lds[FB_LDS_BYTES];
    const int t = threadIdx.x;
    const int lane = t & 63, w = t >> 6, q = (t >> 4) & 3, ln = t & 15;
    const int bid = blockIdx.x;
    const int b = bid & 7, r = bid >> 3;
    const int chalf = r & 1, i = r >> 1;
    const int bi = b * 64 + i;

    float* WYS = (float*)(lds + FB_WYS_OFF);
    {
        const int p = lane, g = w;
        const int pixBase = bi * 64 + p;
        const float ey = exPy[pixBase], ex = exPx[pixBase];
        const float isy = 1.0f / sigmay[pixBase], isx = 1.0f / sigmax[pixBase];
        float sy = 0.0f, sx = 0.0f;
        #pragma unroll
        for (int k = 0; k < 16; ++k) {
            const int u = g * 16 + k;
            const float dy = ((float)u - ey) * isy;
            const float wy = __expf(-0.5f * dy * dy);
            WYS[u * 65 + p] = wy; sy += wy;
        }
        uint* WXH = (uint*)(lds + FB_WXH_OFF);
        #pragma unroll
        for (int j = 0; j < 8; ++j) {
            const int v0 = g * 16 + 2 * j;
            const float dx0 = ((float)v0 - ex) * isx;
            const float dx1 = ((float)(v0 + 1) - ex) * isx;
            const float wx0 = __expf(-0.5f * dx0 * dx0);
            const float wx1 = __expf(-0.5f * dx1 * dx1);
            sx += wx0 + wx1;
            WXH[p * 36 + g * 8 + j] = rn_bf16(wx0) | (rn_bf16(wx1) << 16);
        }
        float* SUMY = (float*)(lds + FB_SUM_OFF);
        float* SUMX = SUMY + 256;
        SUMY[g * 64 + p] = sy; SUMX[g * 64 + p] = sx;
    }
    __syncthreads();
    float* INVZ = (float*)(lds + FB_INVZ_OFF);
    if (t < 64) {
        float* SUMY = (float*)(lds + FB_SUM_OFF);
        float* SUMX = SUMY + 256;
        const float sy = SUMY[t] + SUMY[64 + t] + SUMY[128 + t] + SUMY[192 + t];
        const float sx = SUMX[t] + SUMX[64 + t] + SUMX[128 + t] + SUMX[192 + t];
        INVZ[t] = 1.0f / (sy * sx + 1e-8f);
    }
    __syncthreads();
    short8 bh[4][2];
    #pragma unroll
    for (int nt = 0; nt < 4; ++nt)
        #pragma unroll
        for (int ks = 0; ks < 2; ++ks)
            bh[nt][ks] = *(const short8*)(lds + FB_WXH_OFF + (nt * 16 + ln) * 144 + ks * 64 + q * 16);
    float wyz[4][4];
    #pragma unroll
    for (int nt = 0; nt < 4; ++nt) {
        const float iz = INVZ[nt * 16 + ln];
        #pragma unroll
        for (int rr = 0; rr < 4; ++rr)
            wyz[nt][rr] = WYS[(w * 16 + q * 4 + rr) * 65 + nt * 16 + ln] * iz;
    }
    __syncthreads();
    const int cbase = b * CC + chalf * 16;
    float* RED = (float*)(lds + FB_RED_OFF);
    const float* xrow = inp + (size_t)cbase * 4096 + (w * 16 + ln) * 64 + q * 8;
    #pragma unroll 2
    for (int c = 0; c < 16; ++c) {
        const float4* src = (const float4*)(xrow + (size_t)c * 4096);
        const float4 x0 = src[0], x1 = src[1], x2 = src[8], x3 = src[9];
        union { uint u[4]; short8 s; } Ah0, Al0, Ah1, Al1;
        split_pair(x0.x, x0.y, Ah0.u[0], Al0.u[0]);
        split_pair(x0.z, x0.w, Ah0.u[1], Al0.u[1]);
        split_pair(x1.x, x1.y, Ah0.u[2], Al0.u[2]);
        split_pair(x1.z, x1.w, Ah0.u[3], Al0.u[3]);
        split_pair(x2.x, x2.y, Ah1.u[0], Al1.u[0]);
        split_pair(x2.z, x2.w, Ah1.u[1], Al1.u[1]);
        split_pair(x3.x, x3.y, Ah1.u[2], Al1.u[2]);
        split_pair(x3.z, x3.w, Ah1.u[3], Al1.u[3]);
        f32x4 acc[4];
        #pragma unroll
        for (int nt = 0; nt < 4; ++nt) acc[nt] = (f32x4){0.f, 0.f, 0.f, 0.f};
        #pragma unroll
        for (int nt = 0; nt < 4; ++nt) {
            acc[nt] = __builtin_amdgcn_mfma_f32_16x16x32_bf16(Ah0.s, bh[nt][0], acc[nt], 0, 0, 0);
            acc[nt] = __builtin_amdgcn_mfma_f32_16x16x32_bf16(Al0.s, bh[nt][0], acc[nt], 0, 0, 0);
            acc[nt] = __builtin_amdgcn_mfma_f32_16x16x32_bf16(Ah1.s, bh[nt][1], acc[nt], 0, 0, 0);
            acc[nt] = __builtin_amdgcn_mfma_f32_16x16x32_bf16(Al1.s, bh[nt][1], acc[nt], 0, 0, 0);
        }
        #pragma unroll
        for (int nt = 0; nt < 4; ++nt) {
            float ps = acc[nt][0] * wyz[nt][0] + acc[nt][1] * wyz[nt][1]
                     + acc[nt][2] * wyz[nt][2] + acc[nt][3] * wyz[nt][3];
            ps += __shfl_xor(ps, 16, 64);
            ps += __shfl_xor(ps, 32, 64);
            if (q == 0) RED[c * 256 + w * 64 + nt * 16 + ln] = ps;
        }
    }
    __syncthreads();
    {
        const int kk = t >> 6, p = t & 63;
        #pragma unroll
        for (int g = 0; g < 4; ++g) {
            const int c = g * 4 + kk;
            const float* Rk = RED + c * 256;
            const float o = Rk[p] + Rk[64 + p] + Rk[128 + p] + Rk[192 + p];
            out[(size_t)(cbase + c) * (HH * WW) + i * 64 + p] = o;
        }
    }
}

extern "C" void kernel_launch(void* const* d_in, const int* in_sizes, int n_in,
                              void* d_out, int out_size, void* d_ws, size_t ws_size,
                              hipStream_t stream) {
    const float* inp    = (const float*)d_in[0];
    const float* exPx   = (const float*)d_in[1];
    const float* exPy   = (const float*)d_in[2];
    const float* sigmax = (const float*)d_in[3];
    const float* sigmay = (const float*)d_in[4];
    float* out = (float*)d_out;

    const size_t plane_bytes = (size_t)BB * CC * HH * WW * 2;   // 2 MB bf16 plane
    if (ws_size >= plane_bytes) {
        uint* xhi = (uint*)d_ws;
        // Try the fused cooperative kernel (one dispatch, grid.sync inside).
        void* args[] = {(void*)&inp, (void*)&xhi, (void*)&exPx, (void*)&exPy,
                        (void*)&sigmax, (void*)&sigmay, (void*)&out};
        hipError_t e = hipLaunchCooperativeKernel((const void*)swap_coop_kernel,
                                                  dim3(BB * HH), dim3(256),
                                                  args, 0, stream);
        if (e != hipSuccess) {
            // Fallback: proven R11 two-kernel path.
            hipLaunchKernelGGL(preconvert_kernel, dim3(1024), dim3(256), 0, stream, inp, xhi);
            hipLaunchKernelGGL(swap_mfma_kernel, dim3(BB * HH), dim3(256), 0, stream,
                               xhi, exPx, exPy, sigmax, sigmay, out);
        }
    } else {
        hipLaunchKernelGGL(swap_fused_kernel, dim3(BB * HH * 2), dim3(256), 0, stream,
                           inp, exPx, exPy, sigmax, sigmay, out);
    }
}

// Round 13
// 91.138 us; speedup vs baseline: 1.7579x; 1.7579x over previous
//
#include <hip/hip_runtime.h>

// SwapV2: Gaussian-weighted separable soft gather — single-kernel MFMA.
//   t'[u][p] = sum_v X[u][v] * wx[v][p]     (bf16 MFMA; A = X packed to bf16
//                                            in-register at load, B = wx bf16)
//   out[p]   = sum_u wy[u][p] * t'[u][p] * invZ[p]   (fp32 VALU stage-2)
// R13 = R11 (best, 80.7us) with the preconvert kernel folded into the load
// path: lane stages 16 float4/channel (fbuf), packs to bf16 A-frags with
// round-half-up (half-ULP, ~RNE accuracy), distance-1 channel prefetch.
// Removes one dispatch + graph gap; d_ws unused. Pack VALU lands in stall
// cycles (waves idle >80%). R12's grid.sync cost ~55us — never again.
// Structure: block=(b,i) grid 512, wave = 8 channels x ALL u, wyz[4][4][4]
// fp32 in regs, zero barriers after hoist, one coalesced 256B store/channel.

#define BB 8
#define CC 32
#define HH 64
#define WW 64

typedef __attribute__((ext_vector_type(8))) short short8;   // 8 bf16 (4 VGPRs)
typedef __attribute__((ext_vector_type(4))) float f32x4;    // 4 fp32
typedef unsigned int uint;

__device__ __forceinline__ uint rn_bf16(float f) {
    uint u = __float_as_uint(f);
    return (u + 0x7FFFu + ((u >> 16) & 1u)) >> 16;   // round-to-nearest-even
}
// pack two fp32 -> packed bf16 pair, round-half-up (half-ULP error like RNE;
// 2 adds + shift/and/or, the combine folds to v_perm)
__device__ __forceinline__ uint pack2_rhu(float a, float b) {
    const uint ua = __float_as_uint(a) + 0x8000u;
    const uint ub = __float_as_uint(b) + 0x8000u;
    return (ua >> 16) | (ub & 0xFFFF0000u);
}

// ---------------- LDS layout (bytes) ----------------
// WYS[u][66] fp32 : 64*66*4 = 16896  (stride 66: hoist reads <=2-way banked)
// WXH[p][36] uint : 64*144  =  9216
// SUM 512 fp32    :            2048
// INVZ 64 fp32    :             256
#define WYS_OFF   0
#define WXH_OFF   16896
#define SUM_OFF   26112
#define INVZ_OFF  28160
#define LDS_BYTES 28416

__global__ __launch_bounds__(256, 2)
void swap_kernel(const float* __restrict__ inp,
                 const float* __restrict__ exPx, const float* __restrict__ exPy,
                 const float* __restrict__ sigmax, const float* __restrict__ sigmay,
                 float* __restrict__ out)
{
    __shared__ __align__(16) char lds[LDS_BYTES];
    const int t    = threadIdx.x;
    const int lane = t & 63;
    const int w    = t >> 6;          // wave id -> channel octet
    const int q    = (t >> 4) & 3;    // quad within wave
    const int ln   = t & 15;
    const int bid  = blockIdx.x;      // (i << 3) | b  (XCD heuristic: batch in low bits)
    const int b    = bid & 7;
    const int i    = bid >> 3;
    const int bi   = b * 64 + i;

    // -------- prologue: issue channel-0 fp32 loads before the exp phase --------
    const int cplane0 = b * CC + w * 8;                 // absolute (b,c) plane
    // lane's A-row: u = mt*16 + ln, v = ks*32 + q*8 + j  (fp32 plane, 4096 floats)
    const float4* F4 = (const float4*)(inp + (size_t)cplane0 * 4096 + ln * 64 + q * 8);
    float4 fbuf[4][4];                                  // [mt][ks*2 + half]
    #pragma unroll
    for (int mt = 0; mt < 4; ++mt) {
        fbuf[mt][0] = F4[mt * 256];       // ks=0, j0..3
        fbuf[mt][1] = F4[mt * 256 + 1];   // ks=0, j4..7
        fbuf[mt][2] = F4[mt * 256 + 8];   // ks=1, j0..3
        fbuf[mt][3] = F4[mt * 256 + 9];   // ks=1, j4..7
    }

    float* WYS = (float*)(lds + WYS_OFF);

    // -------- phase 0: per-pixel weights (wy fp32; wx RNE bf16, B-layout) --------
    {
        const int p = lane;           // pixel j of this row
        const int g = w;              // coord group (16 coords)
        const int pixBase = bi * 64 + p;
        const float ey = exPy[pixBase], ex = exPx[pixBase];
        const float isy = 1.0f / sigmay[pixBase], isx = 1.0f / sigmax[pixBase];
        float sy = 0.0f, sx = 0.0f;
        #pragma unroll
        for (int k = 0; k < 16; ++k) {
            const int u = g * 16 + k;
            const float dy = ((float)u - ey) * isy;
            const float wy = __expf(-0.5f * dy * dy);
            WYS[u * 66 + p] = wy;
            sy += wy;
        }
        uint* WXH = (uint*)(lds + WXH_OFF);
        #pragma unroll
        for (int j = 0; j < 8; ++j) {
            const int v0 = g * 16 + 2 * j;
            const float dx0 = ((float)v0       - ex) * isx;
            const float dx1 = ((float)(v0 + 1) - ex) * isx;
            const float wx0 = __expf(-0.5f * dx0 * dx0);
            const float wx1 = __expf(-0.5f * dx1 * dx1);
            sx += wx0 + wx1;
            WXH[p * 36 + g * 8 + j] = rn_bf16(wx0) | (rn_bf16(wx1) << 16);
        }
        float* SUMY = (float*)(lds + SUM_OFF);
        float* SUMX = SUMY + 256;
        SUMY[g * 64 + p] = sy;
        SUMX[g * 64 + p] = sx;
    }
    __syncthreads();
    float* INVZ = (float*)(lds + INVZ_OFF);
    if (t < 64) {
        float* SUMY = (float*)(lds + SUM_OFF);
        float* SUMX = SUMY + 256;
        const float sy = SUMY[t] + SUMY[64 + t] + SUMY[128 + t] + SUMY[192 + t];
        const float sx = SUMX[t] + SUMX[64 + t] + SUMX[128 + t] + SUMX[192 + t];
        INVZ[t] = 1.0f / (sy * sx + 1e-8f);
    }
    __syncthreads();

    // -------- hoist ALL channel-invariants into registers (one-time) --------
    // B-frag (wx): lane holds B[k = ks*32 + q*8 + j][n = nt*16 + ln]
    short8 bh[4][2];
    #pragma unroll
    for (int nt = 0; nt < 4; ++nt)
        #pragma unroll
        for (int ks = 0; ks < 2; ++ks)
            bh[nt][ks] = *(const short8*)(lds + WXH_OFF + (nt * 16 + ln) * 144 + ks * 64 + q * 16);
    // wy*invZ for the FULL u range: wyz[mt][nt][rr] = wy[mt*16+q*4+rr][nt*16+ln]*invZ
    float wyz[4][4][4];
    #pragma unroll
    for (int nt = 0; nt < 4; ++nt) {
        const float iz = INVZ[nt * 16 + ln];
        #pragma unroll
        for (int mt = 0; mt < 4; ++mt)
            #pragma unroll
            for (int rr = 0; rr < 4; ++rr)
                wyz[mt][nt][rr] = WYS[(mt * 16 + q * 4 + rr) * 66 + nt * 16 + ln] * iz;
    }
    // ------- from here on: NO barriers; waves fully independent -------

    // convert channel 0 (fp32 arrived under the exp phase), then issue ch1 loads
    union AU { uint4 v; short8 s; };
    AU acur[4][2];
    #pragma unroll
    for (int mt = 0; mt < 4; ++mt) {
        acur[mt][0].v = (uint4){pack2_rhu(fbuf[mt][0].x, fbuf[mt][0].y),
                                pack2_rhu(fbuf[mt][0].z, fbuf[mt][0].w),
                                pack2_rhu(fbuf[mt][1].x, fbuf[mt][1].y),
                                pack2_rhu(fbuf[mt][1].z, fbuf[mt][1].w)};
        acur[mt][1].v = (uint4){pack2_rhu(fbuf[mt][2].x, fbuf[mt][2].y),
                                pack2_rhu(fbuf[mt][2].z, fbuf[mt][2].w),
                                pack2_rhu(fbuf[mt][3].x, fbuf[mt][3].y),
                                pack2_rhu(fbuf[mt][3].z, fbuf[mt][3].w)};
    }
    #pragma unroll
    for (int mt = 0; mt < 4; ++mt) {
        fbuf[mt][0] = F4[1024 + mt * 256];
        fbuf[mt][1] = F4[1024 + mt * 256 + 1];
        fbuf[mt][2] = F4[1024 + mt * 256 + 8];
        fbuf[mt][3] = F4[1024 + mt * 256 + 9];
    }

    // -------- channel loop: this wave owns 8 channels, ALL of u --------
    float* obase = out + (size_t)cplane0 * 4096 + i * 64 + lane;

    #pragma unroll
    for (int c = 0; c < 8; ++c) {
        float ps[4] = {0.f, 0.f, 0.f, 0.f};
        #pragma unroll
        for (int mt = 0; mt < 4; ++mt) {
            f32x4 acc[4];
            #pragma unroll
            for (int nt = 0; nt < 4; ++nt) acc[nt] = (f32x4){0.f, 0.f, 0.f, 0.f};
            #pragma unroll
            for (int nt = 0; nt < 4; ++nt) {
                acc[nt] = __builtin_amdgcn_mfma_f32_16x16x32_bf16(acur[mt][0].s, bh[nt][0], acc[nt], 0, 0, 0);
                acc[nt] = __builtin_amdgcn_mfma_f32_16x16x32_bf16(acur[mt][1].s, bh[nt][1], acc[nt], 0, 0, 0);
            }
            // u-contraction for this mt tile (rows u = mt*16 + q*4 + rr)
            #pragma unroll
            for (int nt = 0; nt < 4; ++nt)
                ps[nt] += acc[nt][0] * wyz[mt][nt][0] + acc[nt][1] * wyz[mt][nt][1]
                        + acc[nt][2] * wyz[mt][nt][2] + acc[nt][3] * wyz[mt][nt][3];
        }
        // convert channel c+1 (fbuf) -> acur; then prefetch channel c+2 fp32
        if (c < 7) {
            #pragma unroll
            for (int mt = 0; mt < 4; ++mt) {
                acur[mt][0].v = (uint4){pack2_rhu(fbuf[mt][0].x, fbuf[mt][0].y),
                                        pack2_rhu(fbuf[mt][0].z, fbuf[mt][0].w),
                                        pack2_rhu(fbuf[mt][1].x, fbuf[mt][1].y),
                                        pack2_rhu(fbuf[mt][1].z, fbuf[mt][1].w)};
                acur[mt][1].v = (uint4){pack2_rhu(fbuf[mt][2].x, fbuf[mt][2].y),
                                        pack2_rhu(fbuf[mt][2].z, fbuf[mt][2].w),
                                        pack2_rhu(fbuf[mt][3].x, fbuf[mt][3].y),
                                        pack2_rhu(fbuf[mt][3].z, fbuf[mt][3].w)};
            }
        }
        if (c < 6) {
            const int base = (c + 2) * 1024;
            #pragma unroll
            for (int mt = 0; mt < 4; ++mt) {
                fbuf[mt][0] = F4[base + mt * 256];
                fbuf[mt][1] = F4[base + mt * 256 + 1];
                fbuf[mt][2] = F4[base + mt * 256 + 8];
                fbuf[mt][3] = F4[base + mt * 256 + 9];
            }
        }
        // cross-quad reduction: after butterflies every lane holds full sums
        #pragma unroll
        for (int nt = 0; nt < 4; ++nt) {
            ps[nt] += __shfl_xor(ps[nt], 16, 64);
            ps[nt] += __shfl_xor(ps[nt], 32, 64);
        }
        // quad q stores pixel p = q*16 + ln == lane -> one coalesced 256B store
        const float po = (q == 0) ? ps[0] : (q == 1) ? ps[1] : (q == 2) ? ps[2] : ps[3];
        obase[(size_t)c * 4096] = po;
    }
}

extern "C" void kernel_launch(void* const* d_in, const int* in_sizes, int n_in,
                              void* d_out, int out_size, void* d_ws, size_t ws_size,
                              hipStream_t stream) {
    const float* inp    = (const float*)d_in[0];
    const float* exPx   = (const float*)d_in[1];
    const float* exPy   = (const float*)d_in[2];
    const float* sigmax = (const float*)d_in[3];
    const float* sigmay = (const float*)d_in[4];
    float* out = (float*)d_out;

    hipLaunchKernelGGL(swap_kernel, dim3(BB * HH), dim3(256), 0, stream,
                       inp, exPx, exPy, sigmax, sigmay, out);
}

// Round 14
// 80.347 us; speedup vs baseline: 1.9940x; 1.1343x over previous
//
#include <hip/hip_runtime.h>

// SwapV2: Gaussian-weighted separable soft gather — MFMA, wave-owns-channels.
//   t'[u][p] = sum_v X[u][v] * wx[v][p]     (bf16 MFMA, A = X RNE bf16 plane,
//                                            B = wx RNE bf16)
//   out[p]   = sum_u wy[u][p] * t'[u][p] * invZ[p]   (fp32 VALU stage-2)
// R14 = R11 restored verbatim (best, measured 80.70/80.74us twice).
// Final structure after 13 rounds:
//   pass 1: fp32 -> RNE bf16 plane in d_ws (halves c-loop traffic; the single
//           biggest win of the session, R4->R5. Undoing it (R13) cost +10us.)
//   pass 2: block=(b,i) grid 512, wave = 8 channels x ALL of u; all
//           channel-invariants (wx B-frags, wy*invZ) hoisted to registers;
//           zero barriers after hoist, no cross-wave reduction; channels 0-1
//           loaded before the exp phase; distance-2 channel prefetch ring;
//           one coalesced 256B store per channel.
// Failed roads (do not revisit): cooperative grid.sync fusion (+80us, R12),
// in-kernel fp32 convert (+10us, R13), mt-granular prefetch ring (+10us, R10),
// LDS-wy decoupled waves (+15us, R6), launch_bounds occupancy push (+8us, R8).
// Plateau: ~41us harness d_ws re-poison fill + ~40us latency-bound work;
// both pipes <20% busy; 7 structural axes tried, all neutral-or-worse.

#define BB 8
#define CC 32
#define HH 64
#define WW 64

typedef __attribute__((ext_vector_type(8))) short short8;   // 8 bf16 (4 VGPRs)
typedef __attribute__((ext_vector_type(4))) float f32x4;    // 4 fp32
typedef unsigned int uint;

__device__ __forceinline__ uint rn_bf16(float f) {
    uint u = __float_as_uint(f);
    return (u + 0x7FFFu + ((u >> 16) & 1u)) >> 16;   // round-to-nearest-even
}

// ---------------- pass 1: fp32 -> single RNE bf16 plane in d_ws ----------------
__global__ void preconvert_kernel(const float* __restrict__ x, uint* __restrict__ hi)
{
    const int n = BB * CC * HH * WW / 2;     // packed bf16-pair count
    int idx = blockIdx.x * blockDim.x + threadIdx.x;
    for (; idx < n; idx += gridDim.x * blockDim.x) {
        const float2 d = ((const float2*)x)[idx];
        hi[idx] = rn_bf16(d.x) | (rn_bf16(d.y) << 16);
    }
}

// ---------------- main-kernel LDS layout (bytes) ----------------
// WYS[u][66] fp32 : 64*66*4 = 16896  (stride 66: hoist reads <=2-way banked)
// WXH[p][36] uint : 64*144  =  9216
// SUM 512 fp32    :            2048
// INVZ 64 fp32    :             256
#define WYS_OFF   0
#define WXH_OFF   16896
#define SUM_OFF   26112
#define INVZ_OFF  28160
#define LDS_BYTES 28416

__global__ __launch_bounds__(256, 2)
void swap_mfma_kernel(const uint* __restrict__ xhi,
                      const float* __restrict__ exPx, const float* __restrict__ exPy,
                      const float* __restrict__ sigmax, const float* __restrict__ sigmay,
                      float* __restrict__ out)
{
    __shared__ __align__(16) char lds[LDS_BYTES];
    const int t    = threadIdx.x;
    const int lane = t & 63;
    const int w    = t >> 6;          // wave id -> channel octet
    const int q    = (t >> 4) & 3;    // quad within wave
    const int ln   = t & 15;
    const int bid  = blockIdx.x;      // (i << 3) | b  (XCD heuristic: batch in low bits)
    const int b    = bid & 7;
    const int i    = bid >> 3;
    const int bi   = b * 64 + i;

    // -------- prologue: channels 0 AND 1 issued before the exp phase --------
    const int cplane0 = b * CC + w * 8;                 // absolute (b,c) plane
    const uint* xbase = xhi + (size_t)cplane0 * 2048 + ln * 32 + q * 4;
    union AU { uint4 v; short8 s; };
    AU abuf[2][4][2];
    #pragma unroll
    for (int cc = 0; cc < 2; ++cc)
        #pragma unroll
        for (int mt = 0; mt < 4; ++mt) {
            abuf[cc][mt][0].v = *(const uint4*)(xbase + cc * 2048 + mt * 512);        // ks=0
            abuf[cc][mt][1].v = *(const uint4*)(xbase + cc * 2048 + mt * 512 + 16);   // ks=1
        }

    float* WYS = (float*)(lds + WYS_OFF);

    // -------- phase 0: per-pixel weights (wy fp32; wx RNE bf16, B-layout) --------
    {
        const int p = lane;           // pixel j of this row
        const int g = w;              // coord group (16 coords)
        const int pixBase = bi * 64 + p;
        const float ey = exPy[pixBase], ex = exPx[pixBase];
        const float isy = 1.0f / sigmay[pixBase], isx = 1.0f / sigmax[pixBase];
        float sy = 0.0f, sx = 0.0f;
        #pragma unroll
        for (int k = 0; k < 16; ++k) {
            const int u = g * 16 + k;
            const float dy = ((float)u - ey) * isy;
            const float wy = __expf(-0.5f * dy * dy);
            WYS[u * 66 + p] = wy;
            sy += wy;
        }
        uint* WXH = (uint*)(lds + WXH_OFF);
        #pragma unroll
        for (int j = 0; j < 8; ++j) {
            const int v0 = g * 16 + 2 * j;
            const float dx0 = ((float)v0       - ex) * isx;
            const float dx1 = ((float)(v0 + 1) - ex) * isx;
            const float wx0 = __expf(-0.5f * dx0 * dx0);
            const float wx1 = __expf(-0.5f * dx1 * dx1);
            sx += wx0 + wx1;
            WXH[p * 36 + g * 8 + j] = rn_bf16(wx0) | (rn_bf16(wx1) << 16);
        }
        float* SUMY = (float*)(lds + SUM_OFF);
        float* SUMX = SUMY + 256;
        SUMY[g * 64 + p] = sy;
        SUMX[g * 64 + p] = sx;
    }
    __syncthreads();
    float* INVZ = (float*)(lds + INVZ_OFF);
    if (t < 64) {
        float* SUMY = (float*)(lds + SUM_OFF);
        float* SUMX = SUMY + 256;
        const float sy = SUMY[t] + SUMY[64 + t] + SUMY[128 + t] + SUMY[192 + t];
        const float sx = SUMX[t] + SUMX[64 + t] + SUMX[128 + t] + SUMX[192 + t];
        INVZ[t] = 1.0f / (sy * sx + 1e-8f);
    }
    __syncthreads();

    // -------- hoist ALL channel-invariants into registers (one-time) --------
    // B-frag (wx): lane holds B[k = ks*32 + q*8 + j][n = nt*16 + ln]
    short8 bh[4][2];
    #pragma unroll
    for (int nt = 0; nt < 4; ++nt)
        #pragma unroll
        for (int ks = 0; ks < 2; ++ks)
            bh[nt][ks] = *(const short8*)(lds + WXH_OFF + (nt * 16 + ln) * 144 + ks * 64 + q * 16);
    // wy*invZ for the FULL u range: wyz[mt][nt][rr] = wy[mt*16+q*4+rr][nt*16+ln]*invZ
    float wyz[4][4][4];
    #pragma unroll
    for (int nt = 0; nt < 4; ++nt) {
        const float iz = INVZ[nt * 16 + ln];
        #pragma unroll
        for (int mt = 0; mt < 4; ++mt)
            #pragma unroll
            for (int rr = 0; rr < 4; ++rr)
                wyz[mt][nt][rr] = WYS[(mt * 16 + q * 4 + rr) * 66 + nt * 16 + ln] * iz;
    }
    // ------- from here on: NO barriers; waves fully independent -------

    // -------- channel loop: this wave owns 8 channels, ALL of u --------
    float* obase = out + (size_t)cplane0 * 4096 + i * 64 + lane;

    #pragma unroll
    for (int c = 0; c < 8; ++c) {
        float ps[4] = {0.f, 0.f, 0.f, 0.f};
        #pragma unroll
        for (int mt = 0; mt < 4; ++mt) {
            f32x4 acc[4];
            #pragma unroll
            for (int nt = 0; nt < 4; ++nt) acc[nt] = (f32x4){0.f, 0.f, 0.f, 0.f};
            #pragma unroll
            for (int nt = 0; nt < 4; ++nt) {
                acc[nt] = __builtin_amdgcn_mfma_f32_16x16x32_bf16(abuf[c & 1][mt][0].s, bh[nt][0], acc[nt], 0, 0, 0);
                acc[nt] = __builtin_amdgcn_mfma_f32_16x16x32_bf16(abuf[c & 1][mt][1].s, bh[nt][1], acc[nt], 0, 0, 0);
            }
            // u-contraction for this mt tile (rows u = mt*16 + q*4 + rr)
            #pragma unroll
            for (int nt = 0; nt < 4; ++nt)
                ps[nt] += acc[nt][0] * wyz[mt][nt][0] + acc[nt][1] * wyz[mt][nt][1]
                        + acc[nt][2] * wyz[mt][nt][2] + acc[nt][3] * wyz[mt][nt][3];
        }
        // distance-2 prefetch: channel c+2 into slot c&1 (just consumed above)
        if (c + 2 < 8) {
            const uint* xn = xbase + (c + 2) * 2048;
            #pragma unroll
            for (int mt = 0; mt < 4; ++mt) {
                abuf[c & 1][mt][0].v = *(const uint4*)(xn + mt * 512);
                abuf[c & 1][mt][1].v = *(const uint4*)(xn + mt * 512 + 16);
            }
        }
        // cross-quad reduction: after butterflies every lane holds full sums
        #pragma unroll
        for (int nt = 0; nt < 4; ++nt) {
            ps[nt] += __shfl_xor(ps[nt], 16, 64);
            ps[nt] += __shfl_xor(ps[nt], 32, 64);
        }
        // quad q stores pixel p = q*16 + ln == lane -> one coalesced 256B store
        const float po = (q == 0) ? ps[0] : (q == 1) ? ps[1] : (q == 2) ? ps[2] : ps[3];
        obase[(size_t)c * 4096] = po;
    }
}

// ---------------- fallback (R4 proven fused kernel, fp32 loads + A split) ----------------
__device__ __forceinline__ void split_pair(float f0, float f1, uint& hi, uint& lo) {
    const uint u0 = __float_as_uint(f0), u1 = __float_as_uint(f1);
    hi = (u0 >> 16) | (u1 & 0xFFFF0000u);
    const float l0 = f0 - __uint_as_float(u0 & 0xFFFF0000u);
    const float l1 = f1 - __uint_as_float(u1 & 0xFFFF0000u);
    lo = (__float_as_uint(l0) >> 16) | (__float_as_uint(l1) & 0xFFFF0000u);
}

#define FB_WYS_OFF   0
#define FB_WXH_OFF   16640
#define FB_SUM_OFF   25856
#define FB_INVZ_OFF  27904
#define FB_LDS_BYTES 28160
#define FB_RED_OFF   0

__global__ __launch_bounds__(256, 4)
void swap_fused_kernel(const float* __restrict__ inp,
                       const float* __restrict__ exPx, const float* __restrict__ exPy,
                       const float* __restrict__ sigmax, const float* __restrict__ sigmay,
                       float* __restrict__ out)
{
    __shared__ __align__(16) char lds[FB_LDS_BYTES];
    const int t = threadIdx.x;
    const int lane = t & 63, w = t >> 6, q = (t >> 4) & 3, ln = t & 15;
    const int bid = blockIdx.x;
    const int b = bid & 7, r = bid >> 3;
    const int chalf = r & 1, i = r >> 1;
    const int bi = b * 64 + i;

    float* WYS = (float*)(lds + FB_WYS_OFF);
    {
        const int p = lane, g = w;
        const int pixBase = bi * 64 + p;
        const float ey = exPy[pixBase], ex = exPx[pixBase];
        const float isy = 1.0f / sigmay[pixBase], isx = 1.0f / sigmax[pixBase];
        float sy = 0.0f, sx = 0.0f;
        #pragma unroll
        for (int k = 0; k < 16; ++k) {
            const int u = g * 16 + k;
            const float dy = ((float)u - ey) * isy;
            const float wy = __expf(-0.5f * dy * dy);
            WYS[u * 65 + p] = wy; sy += wy;
        }
        uint* WXH = (uint*)(lds + FB_WXH_OFF);
        #pragma unroll
        for (int j = 0; j < 8; ++j) {
            const int v0 = g * 16 + 2 * j;
            const float dx0 = ((float)v0 - ex) * isx;
            const float dx1 = ((float)(v0 + 1) - ex) * isx;
            const float wx0 = __expf(-0.5f * dx0 * dx0);
            const float wx1 = __expf(-0.5f * dx1 * dx1);
            sx += wx0 + wx1;
            WXH[p * 36 + g * 8 + j] = rn_bf16(wx0) | (rn_bf16(wx1) << 16);
        }
        float* SUMY = (float*)(lds + FB_SUM_OFF);
        float* SUMX = SUMY + 256;
        SUMY[g * 64 + p] = sy; SUMX[g * 64 + p] = sx;
    }
    __syncthreads();
    float* INVZ = (float*)(lds + FB_INVZ_OFF);
    if (t < 64) {
        float* SUMY = (float*)(lds + FB_SUM_OFF);
        float* SUMX = SUMY + 256;
        const float sy = SUMY[t] + SUMY[64 + t] + SUMY[128 + t] + SUMY[192 + t];
        const float sx = SUMX[t] + SUMX[64 + t] + SUMX[128 + t] + SUMX[192 + t];
        INVZ[t] = 1.0f / (sy * sx + 1e-8f);
    }
    __syncthreads();
    short8 bh[4][2];
    #pragma unroll
    for (int nt = 0; nt < 4; ++nt)
        #pragma unroll
        for (int ks = 0; ks < 2; ++ks)
            bh[nt][ks] = *(const short8*)(lds + FB_WXH_OFF + (nt * 16 + ln) * 144 + ks * 64 + q * 16);
    float wyz[4][4];
    #pragma unroll
    for (int nt = 0; nt < 4; ++nt) {
        const float iz = INVZ[nt * 16 + ln];
        #pragma unroll
        for (int rr = 0; rr < 4; ++rr)
            wyz[nt][rr] = WYS[(w * 16 + q * 4 + rr) * 65 + nt * 16 + ln] * iz;
    }
    __syncthreads();
    const int cbase = b * CC + chalf * 16;
    float* RED = (float*)(lds + FB_RED_OFF);
    const float* xrow = inp + (size_t)cbase * 4096 + (w * 16 + ln) * 64 + q * 8;
    #pragma unroll 2
    for (int c = 0; c < 16; ++c) {
        const float4* src = (const float4*)(xrow + (size_t)c * 4096);
        const float4 x0 = src[0], x1 = src[1], x2 = src[8], x3 = src[9];
        union { uint u[4]; short8 s; } Ah0, Al0, Ah1, Al1;
        split_pair(x0.x, x0.y, Ah0.u[0], Al0.u[0]);
        split_pair(x0.z, x0.w, Ah0.u[1], Al0.u[1]);
        split_pair(x1.x, x1.y, Ah0.u[2], Al0.u[2]);
        split_pair(x1.z, x1.w, Ah0.u[3], Al0.u[3]);
        split_pair(x2.x, x2.y, Ah1.u[0], Al1.u[0]);
        split_pair(x2.z, x2.w, Ah1.u[1], Al1.u[1]);
        split_pair(x3.x, x3.y, Ah1.u[2], Al1.u[2]);
        split_pair(x3.z, x3.w, Ah1.u[3], Al1.u[3]);
        f32x4 acc[4];
        #pragma unroll
        for (int nt = 0; nt < 4; ++nt) acc[nt] = (f32x4){0.f, 0.f, 0.f, 0.f};
        #pragma unroll
        for (int nt = 0; nt < 4; ++nt) {
            acc[nt] = __builtin_amdgcn_mfma_f32_16x16x32_bf16(Ah0.s, bh[nt][0], acc[nt], 0, 0, 0);
            acc[nt] = __builtin_amdgcn_mfma_f32_16x16x32_bf16(Al0.s, bh[nt][0], acc[nt], 0, 0, 0);
            acc[nt] = __builtin_amdgcn_mfma_f32_16x16x32_bf16(Ah1.s, bh[nt][1], acc[nt], 0, 0, 0);
            acc[nt] = __builtin_amdgcn_mfma_f32_16x16x32_bf16(Al1.s, bh[nt][1], acc[nt], 0, 0, 0);
        }
        #pragma unroll
        for (int nt = 0; nt < 4; ++nt) {
            float ps = acc[nt][0] * wyz[nt][0] + acc[nt][1] * wyz[nt][1]
                     + acc[nt][2] * wyz[nt][2] + acc[nt][3] * wyz[nt][3];
            ps += __shfl_xor(ps, 16, 64);
            ps += __shfl_xor(ps, 32, 64);
            if (q == 0) RED[c * 256 + w * 64 + nt * 16 + ln] = ps;
        }
    }
    __syncthreads();
    {
        const int kk = t >> 6, p = t & 63;
        #pragma unroll
        for (int g = 0; g < 4; ++g) {
            const int c = g * 4 + kk;
            const float* Rk = RED + c * 256;
            const float o = Rk[p] + Rk[64 + p] + Rk[128 + p] + Rk[192 + p];
            out[(size_t)(cbase + c) * (HH * WW) + i * 64 + p] = o;
        }
    }
}

extern "C" void kernel_launch(void* const* d_in, const int* in_sizes, int n_in,
                              void* d_out, int out_size, void* d_ws, size_t ws_size,
                              hipStream_t stream) {
    const float* inp    = (const float*)d_in[0];
    const float* exPx   = (const float*)d_in[1];
    const float* exPy   = (const float*)d_in[2];
    const float* sigmax = (const float*)d_in[3];
    const float* sigmay = (const float*)d_in[4];
    float* out = (float*)d_out;

    const size_t plane_bytes = (size_t)BB * CC * HH * WW * 2;   // 2 MB bf16 plane
    if (ws_size >= plane_bytes) {
        uint* xhi = (uint*)d_ws;
        hipLaunchKernelGGL(preconvert_kernel, dim3(1024), dim3(256), 0, stream, inp, xhi);
        hipLaunchKernelGGL(swap_mfma_kernel, dim3(BB * HH), dim3(256), 0, stream,
                           xhi, exPx, exPy, sigmax, sigmay, out);
    } else {
        hipLaunchKernelGGL(swap_fused_kernel, dim3(BB * HH * 2), dim3(256), 0, stream,
                           inp, exPx, exPy, sigmax, sigmay, out);
    }
}